// Round 4
// baseline (998.102 us; speedup 1.0000x reference)
//
#include <hip/hip_runtime.h>
#include <stdint.h>

// Fused 2-layer LSTM: B=2048, T=512, F=32, H=128, G=512. One WG (512 thr,
// 8 waves) per 8 batch rows; 256 WGs = 1/CU. Skewed schedule: iteration tau
// runs layer-0 step tau AND layer-1 step tau-1.
// ROUND 4: branch-free main loop for MFMA/VALU overlap.
//  Round-3 counters showed MfmaUtil(43%) + VALUBusy(57%) == 100%: the two
//  pipes were fully serialized because the if(do0)/if(do1) guards split the
//  loop body into basic blocks the scheduler can't interleave across.
//  Fix: peel tau=0 (L0 only; h_-1=0 so hh MFMAs drop out) and tau=T_
//  (L1 only); main loop tau=1..T_-1 is one straight-line block ordered
//  L0-MFMA -> L1-ih-MFMA -> L0-gates -> a1h -> L1-hh-MFMA -> L1-gates so the
//  gate transcendental chains can hide under the matrix pipe.
//  Kept from round 3 (proven): 144 register-resident weight regs
//  (Wih0/Whh0/Whh1), Wih1 streamed from slot-contiguous conflict-free LDS
//  image (bank conflicts 7.55e7 -> 8.4e6), kc double-buffered stream,
//  lgkm-only barrier. a1h load deferred past L0 gates to cap peak liveness
//  at ~248 of the 256-reg budget (round 2 proved exceeding it spills).

#define B_ 2048
#define T_ 512
#define F_ 32
#define H_ 128
#define LSTR 144                 // halves per h-buffer row
#define H0SZ (8 * LSTR)          // halves per h buffer
#define W1STR 8192               // halves per wave in streamed-Wih1 LDS image

#define LOG2E 1.4426950408889634f

typedef _Float16 half8 __attribute__((ext_vector_type(8)));
typedef float float4_t __attribute__((ext_vector_type(4)));

// lgkm-only barrier: don't drain vmcnt (global x prefetch stays in flight).
#define BARRIER_LGKM() asm volatile("s_waitcnt lgkmcnt(0)\n\ts_barrier" ::: "memory")

__device__ __forceinline__ float fexp2(float x) {
  float r; asm("v_exp_f32 %0, %1" : "=v"(r) : "v"(x)); return r;
}
__device__ __forceinline__ float frcp(float x) { return __builtin_amdgcn_rcpf(x); }

__device__ __forceinline__ half8 cvt2f4(float4_t a, float4_t b) {
  half8 r;
  r[0] = (_Float16)a[0]; r[1] = (_Float16)a[1]; r[2] = (_Float16)a[2]; r[3] = (_Float16)a[3];
  r[4] = (_Float16)b[0]; r[5] = (_Float16)b[1]; r[6] = (_Float16)b[2]; r[7] = (_Float16)b[3];
  return r;
}
__device__ __forceinline__ half8 load8cvt(const float* p) {
  return cvt2f4(*(const float4_t*)p, *(const float4_t*)(p + 4));
}

__global__ __launch_bounds__(512, 2) void lstm_fused(
    const float* __restrict__ x, const float* __restrict__ Wih0,
    const float* __restrict__ Whh0, const float* __restrict__ b0,
    const float* __restrict__ Wih1, const float* __restrict__ Whh1,
    const float* __restrict__ b1, const float* __restrict__ Wfc,
    const float* __restrict__ bfc, float* __restrict__ out)
{
  __shared__ __attribute__((aligned(16))) _Float16 lds_w1[8 * W1STR];  // 131072 B
  __shared__ __attribute__((aligned(16))) _Float16 lds_h0[2 * H0SZ];   // 4608 B
  __shared__ __attribute__((aligned(16))) _Float16 lds_h1[2 * H0SZ];   // 4608 B
  __shared__ float lds_fc[8][8];

  const int tid  = threadIdx.x;
  const int w    = tid >> 6;
  const int lane = tid & 63;
  const int n    = lane & 15;
  const int q    = lane >> 4;
  const int rbase = (int)blockIdx.x * 8;
  const int rload = rbase + (n & 7);
  const int rsh  = (q >> 1) * 2;            // acc regs this lane finalizes
  const int rowq = (q & 1) * 4;             // base output row
  const int colg = w * 16 + n;              // this lane's h-column
  const int aoff = (n & 7) * LSTR + q * 8;  // A-frag read offset (halves)

  // ---- setup: Wih0/Whh0/Whh1 -> regs; Wih1 -> slot-contiguous LDS ----
  // Image: per wave block of 8192 halves; slot (kc*4+j) stride 512 halves;
  // lane (q,n) owns halves q*128+n*8 -> each wave reads 1024 contiguous
  // bytes per ds_read_b128 slot: conflict-free.
  half8 bwih0[4], bwhh0[4][4], bwhh1[4][4];
  _Float16* w1base = lds_w1 + w * W1STR + q * 128 + n * 8;
#pragma unroll
  for (int j = 0; j < 4; ++j) {
    const int g = j * H_ + colg;            // == (j*8+w)*16+n
    bwih0[j] = load8cvt(Wih0 + g * F_ + q * 8);
#pragma unroll
    for (int kc = 0; kc < 4; ++kc) {
      bwhh0[j][kc] = load8cvt(Whh0 + g * H_ + kc * 32 + q * 8);
      bwhh1[j][kc] = load8cvt(Whh1 + g * H_ + kc * 32 + q * 8);
      *(half8*)(w1base + (kc * 4 + j) * 512) = load8cvt(Wih1 + g * H_ + kc * 32 + q * 8);
    }
  }
  // folded gate biases (log2 domain): sig(z+b)=rcp(1+2^(-z*log2e - b*log2e)),
  // tanh(z+b)=1-2*rcp(1+2^(2z*log2e + 2b*log2e))
  const float cI0 = -b0[0 * H_ + colg] * LOG2E;
  const float cF0 = -b0[1 * H_ + colg] * LOG2E;
  const float cG0 =  b0[2 * H_ + colg] * (2.0f * LOG2E);
  const float cO0 = -b0[3 * H_ + colg] * LOG2E;
  const float cI1 = -b1[0 * H_ + colg] * LOG2E;
  const float cF1 = -b1[1 * H_ + colg] * LOG2E;
  const float cG1 =  b1[2 * H_ + colg] * (2.0f * LOG2E);
  const float cO1 = -b1[3 * H_ + colg] * LOG2E;

  for (int i = tid; i < 2 * H0SZ; i += 512) { lds_h0[i] = (_Float16)0.0f; lds_h1[i] = (_Float16)0.0f; }
  __syncthreads();

  const float4_t zC = {0.f, 0.f, 0.f, 0.f};
  float c00 = 0.f, c01 = 0.f;      // layer-0 cell state (2 rows)
  float c10 = 0.f, c11 = 0.f;      // layer-1 cell state

  const float* xptr = x + rload * (T_ * F_) + q * 8;
  float4_t xrA = *(const float4_t*)(xptr);
  float4_t xrB = *(const float4_t*)(xptr + 4);

  // gate evaluator: 2 rows, log2-domain folded biases, writes h as f16
  auto GATES = [&](float4_t (&acc)[4], float cI, float cF, float cG, float cO,
                   float& ca, float& cb, _Float16* dst) {
#pragma unroll
    for (int rr = 0; rr < 2; ++rr) {
      const int ri = rsh + rr;
      const float gi = frcp(1.0f + fexp2(__builtin_fmaf(acc[0][ri], -LOG2E, cI)));
      const float gf = frcp(1.0f + fexp2(__builtin_fmaf(acc[1][ri], -LOG2E, cF)));
      const float gg = 1.0f - 2.0f * frcp(1.0f + fexp2(__builtin_fmaf(acc[2][ri], 2.0f * LOG2E, cG)));
      const float go = frcp(1.0f + fexp2(__builtin_fmaf(acc[3][ri], -LOG2E, cO)));
      float& cc = rr ? cb : ca;
      cc = __builtin_fmaf(gf, cc, gi * gg);
      const float th = 1.0f - 2.0f * frcp(1.0f + fexp2(cc * (2.0f * LOG2E)));
      dst[(rowq + ri) * LSTR + colg] = (_Float16)(go * th);
    }
  };

  // ---- peel tau=0: layer-0 step 0 only (h_-1 = 0 -> skip hh MFMAs) ----
  {
    float4_t acc0[4];
    half8 ax = cvt2f4(xrA, xrB);
#pragma unroll
    for (int j = 0; j < 4; ++j)
      acc0[j] = __builtin_amdgcn_mfma_f32_16x16x32_f16(ax, bwih0[j], zC, 0, 0, 0);
    xrA = *(const float4_t*)(xptr + F_);            // prefetch x(1)
    xrB = *(const float4_t*)(xptr + F_ + 4);
    GATES(acc0, cI0, cF0, cG0, cO0, c00, c01, lds_h0 /* pw=0 buf */);
    BARRIER_LGKM();
  }

  // ---- main loop tau = 1..T_-1: straight-line, no internal branches ----
#pragma unroll 1
  for (int tau = 1; tau < T_; ++tau) {
    const int pw = tau & 1;
    _Float16* h0rd = lds_h0 + (pw ^ 1) * H0SZ;   // h0(tau-1)
    _Float16* h0wr = lds_h0 + pw * H0SZ;         // h0(tau)
    _Float16* h1rd = lds_h1 + pw * H0SZ;         // h1(tau-2)
    _Float16* h1wr = lds_h1 + (pw ^ 1) * H0SZ;   // h1(tau-1)

    half8 ah[4];                                  // h0(tau-1): shared A-frag
#pragma unroll
    for (int kc = 0; kc < 4; ++kc)
      ah[kc] = *(const half8*)(h0rd + aoff + kc * 32);
    half8 w1a[4];                                 // Wih1 kc=0 frags (streamed)
#pragma unroll
    for (int j = 0; j < 4; ++j)
      w1a[j] = *(const half8*)(w1base + (0 * 4 + j) * 512);

    // layer 0, step tau
    float4_t acc0[4];
    half8 ax = cvt2f4(xrA, xrB);
#pragma unroll
    for (int j = 0; j < 4; ++j)
      acc0[j] = __builtin_amdgcn_mfma_f32_16x16x32_f16(ax, bwih0[j], zC, 0, 0, 0);
#pragma unroll
    for (int kc = 0; kc < 4; ++kc)
#pragma unroll
      for (int j = 0; j < 4; ++j)
        acc0[j] = __builtin_amdgcn_mfma_f32_16x16x32_f16(ah[kc], bwhh0[j][kc], acc0[j], 0, 0, 0);
    const int tn = (tau + 1 < T_) ? tau + 1 : T_ - 1;     // x prefetch (clamped)
    xrA = *(const float4_t*)(xptr + tn * F_);
    xrB = *(const float4_t*)(xptr + tn * F_ + 4);

    // layer 1, step tau-1: ih part (kc double-buffered stream)
    float4_t acc1[4];
    half8 w1b[4];
#pragma unroll
    for (int j = 0; j < 4; ++j)
      w1b[j] = *(const half8*)(w1base + (1 * 4 + j) * 512);
#pragma unroll
    for (int j = 0; j < 4; ++j)                 // ih kc=0 (w1a dies)
      acc1[j] = __builtin_amdgcn_mfma_f32_16x16x32_f16(ah[0], w1a[j], zC, 0, 0, 0);
#pragma unroll
    for (int j = 0; j < 4; ++j)
      w1a[j] = *(const half8*)(w1base + (2 * 4 + j) * 512);
#pragma unroll
    for (int j = 0; j < 4; ++j)                 // ih kc=1 (w1b dies)
      acc1[j] = __builtin_amdgcn_mfma_f32_16x16x32_f16(ah[1], w1b[j], acc1[j], 0, 0, 0);
#pragma unroll
    for (int j = 0; j < 4; ++j)
      w1b[j] = *(const half8*)(w1base + (3 * 4 + j) * 512);
#pragma unroll
    for (int j = 0; j < 4; ++j)                 // ih kc=2
      acc1[j] = __builtin_amdgcn_mfma_f32_16x16x32_f16(ah[2], w1a[j], acc1[j], 0, 0, 0);
#pragma unroll
    for (int j = 0; j < 4; ++j)                 // ih kc=3 (ah dies)
      acc1[j] = __builtin_amdgcn_mfma_f32_16x16x32_f16(ah[3], w1b[j], acc1[j], 0, 0, 0);

    // layer-0 gates: trans chain can hide under the surrounding MFMA issue
    GATES(acc0, cI0, cF0, cG0, cO0, c00, c01, h0wr);

    half8 a1h[4];                               // h1(tau-2) (deferred load:
#pragma unroll                                  //  caps peak reg liveness)
    for (int kc = 0; kc < 4; ++kc)
      a1h[kc] = *(const half8*)(h1rd + aoff + kc * 32);
#pragma unroll
    for (int kc = 0; kc < 4; ++kc)              // hh (register-resident B)
#pragma unroll
      for (int j = 0; j < 4; ++j)
        acc1[j] = __builtin_amdgcn_mfma_f32_16x16x32_f16(a1h[kc], bwhh1[j][kc], acc1[j], 0, 0, 0);

    GATES(acc1, cI1, cF1, cG1, cO1, c10, c11, h1wr);
    BARRIER_LGKM();
  }

  // ---- peel tau=T_: layer-1 step T_-1 only ----
  {
    // T_ even -> pw=0: h0rd=buf1=h0(T_-1), h1rd=buf0=h1(T_-2), h1wr=buf1
    _Float16* h0rd = lds_h0 + H0SZ;
    _Float16* h1rd = lds_h1;
    _Float16* h1wr = lds_h1 + H0SZ;

    half8 ah[4];
#pragma unroll
    for (int kc = 0; kc < 4; ++kc)
      ah[kc] = *(const half8*)(h0rd + aoff + kc * 32);
    float4_t acc1[4];
    half8 w1a[4], w1b[4];
#pragma unroll
    for (int j = 0; j < 4; ++j)
      w1a[j] = *(const half8*)(w1base + (0 * 4 + j) * 512);
#pragma unroll
    for (int j = 0; j < 4; ++j)
      w1b[j] = *(const half8*)(w1base + (1 * 4 + j) * 512);
#pragma unroll
    for (int j = 0; j < 4; ++j)
      acc1[j] = __builtin_amdgcn_mfma_f32_16x16x32_f16(ah[0], w1a[j], zC, 0, 0, 0);
#pragma unroll
    for (int j = 0; j < 4; ++j)
      w1a[j] = *(const half8*)(w1base + (2 * 4 + j) * 512);
#pragma unroll
    for (int j = 0; j < 4; ++j)
      acc1[j] = __builtin_amdgcn_mfma_f32_16x16x32_f16(ah[1], w1b[j], acc1[j], 0, 0, 0);
#pragma unroll
    for (int j = 0; j < 4; ++j)
      w1b[j] = *(const half8*)(w1base + (3 * 4 + j) * 512);
#pragma unroll
    for (int j = 0; j < 4; ++j)
      acc1[j] = __builtin_amdgcn_mfma_f32_16x16x32_f16(ah[2], w1a[j], acc1[j], 0, 0, 0);
#pragma unroll
    for (int j = 0; j < 4; ++j)
      acc1[j] = __builtin_amdgcn_mfma_f32_16x16x32_f16(ah[3], w1b[j], acc1[j], 0, 0, 0);
    half8 a1h[4];
#pragma unroll
    for (int kc = 0; kc < 4; ++kc)
      a1h[kc] = *(const half8*)(h1rd + aoff + kc * 32);
#pragma unroll
    for (int kc = 0; kc < 4; ++kc)
#pragma unroll
      for (int j = 0; j < 4; ++j)
        acc1[j] = __builtin_amdgcn_mfma_f32_16x16x32_f16(a1h[kc], bwhh1[j][kc], acc1[j], 0, 0, 0);
    GATES(acc1, cI1, cF1, cG1, cO1, c10, c11, h1wr);
    asm volatile("s_waitcnt lgkmcnt(0)" ::: "memory");   // own writes visible
  }

  // ---- FC head: out[row] = sum_c h1_last[row][c]*Wfc[c] + bfc ----
  // h1(T-1) is in lds_h1+H0SZ; each lane reads back the two values it wrote.
  const float wfcv = Wfc[colg];
  float p0 = (float)lds_h1[H0SZ + (rowq + rsh + 0) * LSTR + colg] * wfcv;
  float p1 = (float)lds_h1[H0SZ + (rowq + rsh + 1) * LSTR + colg] * wfcv;
#pragma unroll
  for (int m = 1; m < 16; m <<= 1) {
    p0 += __shfl_xor(p0, m);
    p1 += __shfl_xor(p1, m);
  }
  if (n == 0) {
    lds_fc[w][rowq + rsh + 0] = p0;
    lds_fc[w][rowq + rsh + 1] = p1;
  }
  __syncthreads();
  if (tid < 8) {
    float s = bfc[0];
#pragma unroll
    for (int wv = 0; wv < 8; ++wv) s += lds_fc[wv][tid];
    out[rbase + tid] = s;
  }
}

extern "C" void kernel_launch(void* const* d_in, const int* in_sizes, int n_in,
                              void* d_out, int out_size, void* d_ws, size_t ws_size,
                              hipStream_t stream) {
  const float* x    = (const float*)d_in[0];
  const float* Wih0 = (const float*)d_in[1];
  const float* Whh0 = (const float*)d_in[2];
  const float* b0   = (const float*)d_in[3];
  const float* Wih1 = (const float*)d_in[4];
  const float* Whh1 = (const float*)d_in[5];
  const float* b1   = (const float*)d_in[6];
  const float* Wfc  = (const float*)d_in[7];
  const float* bfc  = (const float*)d_in[8];
  float* outp = (float*)d_out;
  (void)d_ws; (void)ws_size;

  lstm_fused<<<B_ / 8, 512, 0, stream>>>(x, Wih0, Whh0, b0, Wih1, Whh1, b1,
                                         Wfc, bfc, outp);
}

// Round 5
// 968.381 us; speedup vs baseline: 1.0307x; 1.0307x over previous
//
#include <hip/hip_runtime.h>
#include <stdint.h>

// Fused 2-layer LSTM: B=2048, T=512, F=32, H=128, G=512. One WG (512 thr,
// 8 waves) per 8 batch rows; 256 WGs = 1/CU.
// ROUND 5: WAVE SPECIALIZATION BY LAYER.
//  Rounds 3/4 measured MfmaUtil+VALUBusy == 100-102%: with all 8 waves
//  running identical code between identical barriers, each SIMD's two waves
//  reach their MFMA phase and their gate-VALU phase simultaneously -> pipes
//  time-slice (iter = M + V). Gates can't be deferred across the barrier
//  (all-to-all h-column consumption), so the fix is ROLE-SPLIT:
//   waves 0-3 ("L0-waves"): layer 0 only. 128 gate-cols each (2 col-groups
//     x 4 gate types): Wih0 (32 regs) + Whh0 (128 regs) register-resident;
//     40 MFMA/iter; read x, write h0.
//   waves 4-7 ("L1-waves"): layer 1 only (skewed: step tau-1 at iter tau).
//     Whh1 (128 regs) register-resident; Wih1 streamed from a per-wave
//     32-slot conflict-free LDS image (32 ds_read_b128/iter, kc-dbuf);
//     64 MFMA/iter; write h1.
//  Wave->SIMD mapping is round-robin (wave%4), so SIMD k holds wave k (L0)
//  + wave k+4 (L1): different code -> one wave's gate VALU overlaps the
//  other's MFMAs. Totals per SIMD unchanged; only overlap changes.
//  Roles live in disjoint top-level branches (disjoint weight live-ranges,
//  ~235/246 peak regs each < 256 at 2 waves/SIMD). Both branches execute
//  identical barrier counts (prologue 1 + 511 loop) -> legal s_barrier use.
//  Kept from rounds 3/4 (proven): slot-contiguous conflict-free Wih1 image
//  (conflicts 7.55e7 -> 8.4e6), kc double-buffer, lgkm-only barrier,
//  log2-domain folded-bias gates, grp-sequential acc (16 live acc regs).

#define B_ 2048
#define T_ 512
#define F_ 32
#define H_ 128
#define LSTR 144                 // halves per h-buffer row
#define H0SZ (8 * LSTR)          // halves per h buffer
#define W1SLOT 512               // halves per Wih1 image slot (1 KB)
#define W1WAVE (32 * W1SLOT)     // 32 slots per L1-wave (32 KB)

#define LOG2E 1.4426950408889634f

typedef _Float16 half8 __attribute__((ext_vector_type(8)));
typedef float float4_t __attribute__((ext_vector_type(4)));

// lgkm-only barrier: don't drain vmcnt (global x prefetch stays in flight).
#define BARRIER_LGKM() asm volatile("s_waitcnt lgkmcnt(0)\n\ts_barrier" ::: "memory")

__device__ __forceinline__ float fexp2(float x) {
  float r; asm("v_exp_f32 %0, %1" : "=v"(r) : "v"(x)); return r;
}
__device__ __forceinline__ float frcp(float x) { return __builtin_amdgcn_rcpf(x); }

__device__ __forceinline__ half8 cvt2f4(float4_t a, float4_t b) {
  half8 r;
  r[0] = (_Float16)a[0]; r[1] = (_Float16)a[1]; r[2] = (_Float16)a[2]; r[3] = (_Float16)a[3];
  r[4] = (_Float16)b[0]; r[5] = (_Float16)b[1]; r[6] = (_Float16)b[2]; r[7] = (_Float16)b[3];
  return r;
}
__device__ __forceinline__ half8 load8cvt(const float* p) {
  return cvt2f4(*(const float4_t*)p, *(const float4_t*)(p + 4));
}

__global__ __launch_bounds__(512, 2) void lstm_fused(
    const float* __restrict__ x, const float* __restrict__ Wih0,
    const float* __restrict__ Whh0, const float* __restrict__ b0,
    const float* __restrict__ Wih1, const float* __restrict__ Whh1,
    const float* __restrict__ b1, const float* __restrict__ Wfc,
    const float* __restrict__ bfc, float* __restrict__ out)
{
  __shared__ __attribute__((aligned(16))) _Float16 lds_w1[4 * W1WAVE];  // 131072 B
  __shared__ __attribute__((aligned(16))) _Float16 lds_h0[2 * H0SZ];    // 4608 B
  __shared__ __attribute__((aligned(16))) _Float16 lds_h1[2 * H0SZ];    // 4608 B
  __shared__ float lds_fc[8][8];

  const int tid  = threadIdx.x;
  const int w    = tid >> 6;
  const int lane = tid & 63;
  const int n    = lane & 15;
  const int q    = lane >> 4;
  const int rbase = (int)blockIdx.x * 8;
  const int rsh  = (q >> 1) * 2;            // acc rows this lane finalizes
  const int rowq = (q & 1) * 4;             // base output row
  const int wq   = w & 3;                   // role-local wave index
  const int hc0  = wq * 16 + n;             // col-group 0 h-column
  const int hc1  = hc0 + 64;                // col-group 1 h-column
  const int aoff = (n & 7) * LSTR + q * 8;  // A-frag read offset (halves)
  const bool isL0 = (w < 4);

  // zero only what is read before first written: h1 (h1(-1) must be 0).
  // h0 buf0 is fully written by the L0 prologue; h0 buf1 written at tau=1
  // before its first read at tau=2 -> no h0 zeroing (avoids a setup race
  // with the prologue's h0 writes; the first in-branch barrier orders the
  // h1 zeroing against its tau=1 read).
  for (int i = tid; i < 2 * H0SZ; i += 512) lds_h1[i] = (_Float16)0.0f;

  const float4_t zC = {0.f, 0.f, 0.f, 0.f};

  // gate evaluator: 2 rows, log2-domain folded biases, writes h as f16.
  // sig(z+b)=rcp(1+2^(-z*log2e - b*log2e)); tanh(z+b)=1-2*rcp(1+2^(2(z+b)log2e))
  auto GATES = [&](const float4_t (&acc)[4], float cI, float cF, float cG,
                   float cO, float& ca, float& cb, _Float16* dst, int hcol) {
#pragma unroll
    for (int rr = 0; rr < 2; ++rr) {
      const int ri = rsh + rr;
      const float gi = frcp(1.0f + fexp2(__builtin_fmaf(acc[0][ri], -LOG2E, cI)));
      const float gf = frcp(1.0f + fexp2(__builtin_fmaf(acc[1][ri], -LOG2E, cF)));
      const float gg = 1.0f - 2.0f * frcp(1.0f + fexp2(__builtin_fmaf(acc[2][ri], 2.0f * LOG2E, cG)));
      const float go = frcp(1.0f + fexp2(__builtin_fmaf(acc[3][ri], -LOG2E, cO)));
      float& cc = rr ? cb : ca;
      cc = __builtin_fmaf(gf, cc, gi * gg);
      const float th = 1.0f - 2.0f * frcp(1.0f + fexp2(cc * (2.0f * LOG2E)));
      dst[(rowq + ri) * LSTR + hcol] = (_Float16)(go * th);
    }
  };

  if (isL0) {
    // ================= L0-waves: layer 0, 128 gate-cols each =============
    half8 bwih0[2][4], bwhh0[2][4][4];      // 32 + 128 regs
    float cI[2], cF[2], cG[2], cO[2];
#pragma unroll
    for (int grp = 0; grp < 2; ++grp) {
      const int hcol = grp ? hc1 : hc0;
#pragma unroll
      for (int gt = 0; gt < 4; ++gt) {
        const int g = gt * H_ + hcol;
        bwih0[grp][gt] = load8cvt(Wih0 + g * F_ + q * 8);
#pragma unroll
        for (int kc = 0; kc < 4; ++kc)
          bwhh0[grp][gt][kc] = load8cvt(Whh0 + g * H_ + kc * 32 + q * 8);
      }
      cI[grp] = -b0[0 * H_ + hcol] * LOG2E;
      cF[grp] = -b0[1 * H_ + hcol] * LOG2E;
      cG[grp] =  b0[2 * H_ + hcol] * (2.0f * LOG2E);
      cO[grp] = -b0[3 * H_ + hcol] * LOG2E;
    }
    float c0a[2] = {0.f, 0.f}, c0b[2] = {0.f, 0.f};

    const float* xptr = x + (rbase + (n & 7)) * (T_ * F_) + q * 8;
    float4_t xrA = *(const float4_t*)(xptr);
    float4_t xrB = *(const float4_t*)(xptr + 4);

    // ---- prologue tau=0: ih only (h_-1 = 0) ----
    {
      half8 ax = cvt2f4(xrA, xrB);
#pragma unroll
      for (int grp = 0; grp < 2; ++grp) {
        float4_t acc[4];
#pragma unroll
        for (int gt = 0; gt < 4; ++gt)
          acc[gt] = __builtin_amdgcn_mfma_f32_16x16x32_f16(ax, bwih0[grp][gt], zC, 0, 0, 0);
        GATES(acc, cI[grp], cF[grp], cG[grp], cO[grp], c0a[grp], c0b[grp],
              lds_h0 /* buf0 */, grp ? hc1 : hc0);
      }
      xrA = *(const float4_t*)(xptr + F_);
      xrB = *(const float4_t*)(xptr + F_ + 4);
      BARRIER_LGKM();
    }

    // ---- main loop tau = 1..T_-1 ----
#pragma unroll 1
    for (int tau = 1; tau < T_; ++tau) {
      const int pw = tau & 1;
      _Float16* h0rd = lds_h0 + (pw ^ 1) * H0SZ;
      _Float16* h0wr = lds_h0 + pw * H0SZ;

      half8 ah[4];
#pragma unroll
      for (int kc = 0; kc < 4; ++kc)
        ah[kc] = *(const half8*)(h0rd + aoff + kc * 32);
      half8 ax = cvt2f4(xrA, xrB);

#pragma unroll
      for (int grp = 0; grp < 2; ++grp) {
        float4_t acc[4];
#pragma unroll
        for (int gt = 0; gt < 4; ++gt)
          acc[gt] = __builtin_amdgcn_mfma_f32_16x16x32_f16(ax, bwih0[grp][gt], zC, 0, 0, 0);
#pragma unroll
        for (int kc = 0; kc < 4; ++kc)
#pragma unroll
          for (int gt = 0; gt < 4; ++gt)
            acc[gt] = __builtin_amdgcn_mfma_f32_16x16x32_f16(ah[kc], bwhh0[grp][gt][kc], acc[gt], 0, 0, 0);
        if (grp == 0) {                         // x prefetch under grp0 MFMAs
          const int tn = (tau + 1 < T_) ? tau + 1 : T_ - 1;
          xrA = *(const float4_t*)(xptr + tn * F_);
          xrB = *(const float4_t*)(xptr + tn * F_ + 4);
        }
        GATES(acc, cI[grp], cF[grp], cG[grp], cO[grp], c0a[grp], c0b[grp],
              h0wr, grp ? hc1 : hc0);
      }
      BARRIER_LGKM();
    }
    // epilogue: nothing (L1-waves run step T_-1); fall through to join.
  } else {
    // ================= L1-waves: layer 1, 128 gate-cols each =============
    half8 bwhh1[2][4][4];                    // 128 regs
    float cI[2], cF[2], cG[2], cO[2];
    _Float16* w1base = lds_w1 + wq * W1WAVE + q * 128 + n * 8;
#pragma unroll
    for (int grp = 0; grp < 2; ++grp) {
      const int hcol = grp ? hc1 : hc0;
#pragma unroll
      for (int gt = 0; gt < 4; ++gt) {
        const int g = gt * H_ + hcol;
#pragma unroll
        for (int kc = 0; kc < 4; ++kc) {
          bwhh1[grp][gt][kc] = load8cvt(Whh1 + g * H_ + kc * 32 + q * 8);
          // slot-contiguous image: slot (grp*16+kc*4+gt), lane region
          // q*128+n*8 -> each wave ds_read_b128 slot = 1024 contiguous B.
          *(half8*)(w1base + (grp * 16 + kc * 4 + gt) * W1SLOT) =
              load8cvt(Wih1 + g * H_ + kc * 32 + q * 8);
        }
      }
      cI[grp] = -b1[0 * H_ + hcol] * LOG2E;
      cF[grp] = -b1[1 * H_ + hcol] * LOG2E;
      cG[grp] =  b1[2 * H_ + hcol] * (2.0f * LOG2E);
      cO[grp] = -b1[3 * H_ + hcol] * LOG2E;
    }
    float c1a[2] = {0.f, 0.f}, c1b[2] = {0.f, 0.f};

    BARRIER_LGKM();                            // matches L0 prologue barrier

    // ---- main loop tau = 1..T_-1: runs layer-1 step tau-1 ----
#pragma unroll 1
    for (int tau = 1; tau < T_; ++tau) {
      const int pw = tau & 1;
      _Float16* h0rd = lds_h0 + (pw ^ 1) * H0SZ;   // h0(tau-1)
      _Float16* h1rd = lds_h1 + pw * H0SZ;         // h1(tau-2)
      _Float16* h1wr = lds_h1 + (pw ^ 1) * H0SZ;   // h1(tau-1)

      half8 ah[4], a1h[4];
#pragma unroll
      for (int kc = 0; kc < 4; ++kc) {
        ah[kc]  = *(const half8*)(h0rd + aoff + kc * 32);
        a1h[kc] = *(const half8*)(h1rd + aoff + kc * 32);
      }
#pragma unroll
      for (int grp = 0; grp < 2; ++grp) {
        half8 wa[4], wb[4];
        float4_t acc[4];
#pragma unroll
        for (int gt = 0; gt < 4; ++gt)
          wa[gt] = *(const half8*)(w1base + (grp * 16 + 0 * 4 + gt) * W1SLOT);
#pragma unroll
        for (int gt = 0; gt < 4; ++gt)
          wb[gt] = *(const half8*)(w1base + (grp * 16 + 1 * 4 + gt) * W1SLOT);
#pragma unroll
        for (int gt = 0; gt < 4; ++gt)      // ih kc=0 (wa dies)
          acc[gt] = __builtin_amdgcn_mfma_f32_16x16x32_f16(ah[0], wa[gt], zC, 0, 0, 0);
#pragma unroll
        for (int gt = 0; gt < 4; ++gt)
          wa[gt] = *(const half8*)(w1base + (grp * 16 + 2 * 4 + gt) * W1SLOT);
#pragma unroll
        for (int gt = 0; gt < 4; ++gt)      // ih kc=1 (wb dies)
          acc[gt] = __builtin_amdgcn_mfma_f32_16x16x32_f16(ah[1], wb[gt], acc[gt], 0, 0, 0);
#pragma unroll
        for (int gt = 0; gt < 4; ++gt)
          wb[gt] = *(const half8*)(w1base + (grp * 16 + 3 * 4 + gt) * W1SLOT);
#pragma unroll
        for (int gt = 0; gt < 4; ++gt)      // ih kc=2
          acc[gt] = __builtin_amdgcn_mfma_f32_16x16x32_f16(ah[2], wa[gt], acc[gt], 0, 0, 0);
#pragma unroll
        for (int gt = 0; gt < 4; ++gt)      // ih kc=3
          acc[gt] = __builtin_amdgcn_mfma_f32_16x16x32_f16(ah[3], wb[gt], acc[gt], 0, 0, 0);
#pragma unroll
        for (int kc = 0; kc < 4; ++kc)      // hh (register-resident B)
#pragma unroll
          for (int gt = 0; gt < 4; ++gt)
            acc[gt] = __builtin_amdgcn_mfma_f32_16x16x32_f16(a1h[kc], bwhh1[grp][gt][kc], acc[gt], 0, 0, 0);
        GATES(acc, cI[grp], cF[grp], cG[grp], cO[grp], c1a[grp], c1b[grp],
              h1wr, grp ? hc1 : hc0);
      }
      BARRIER_LGKM();
    }

    // ---- epilogue: layer-1 step T_-1 (no trailing barrier; join syncs) ----
    {
      _Float16* h0rd = lds_h0 + H0SZ;   // h0(T_-1): tau=T_-1 (pw=1) wrote buf1
      _Float16* h1rd = lds_h1;          // h1(T_-2): tau=T_-1 wrote buf0
      _Float16* h1wr = lds_h1 + H0SZ;   // h1(T_-1) -> buf1 (FC reads here)

      half8 ah[4], a1h[4];
#pragma unroll
      for (int kc = 0; kc < 4; ++kc) {
        ah[kc]  = *(const half8*)(h0rd + aoff + kc * 32);
        a1h[kc] = *(const half8*)(h1rd + aoff + kc * 32);
      }
#pragma unroll
      for (int grp = 0; grp < 2; ++grp) {
        half8 wa[4], wb[4];
        float4_t acc[4];
#pragma unroll
        for (int gt = 0; gt < 4; ++gt)
          wa[gt] = *(const half8*)(w1base + (grp * 16 + 0 * 4 + gt) * W1SLOT);
#pragma unroll
        for (int gt = 0; gt < 4; ++gt)
          wb[gt] = *(const half8*)(w1base + (grp * 16 + 1 * 4 + gt) * W1SLOT);
#pragma unroll
        for (int gt = 0; gt < 4; ++gt)
          acc[gt] = __builtin_amdgcn_mfma_f32_16x16x32_f16(ah[0], wa[gt], zC, 0, 0, 0);
#pragma unroll
        for (int gt = 0; gt < 4; ++gt)
          wa[gt] = *(const half8*)(w1base + (grp * 16 + 2 * 4 + gt) * W1SLOT);
#pragma unroll
        for (int gt = 0; gt < 4; ++gt)
          acc[gt] = __builtin_amdgcn_mfma_f32_16x16x32_f16(ah[1], wb[gt], acc[gt], 0, 0, 0);
#pragma unroll
        for (int gt = 0; gt < 4; ++gt)
          wb[gt] = *(const half8*)(w1base + (grp * 16 + 3 * 4 + gt) * W1SLOT);
#pragma unroll
        for (int gt = 0; gt < 4; ++gt)
          acc[gt] = __builtin_amdgcn_mfma_f32_16x16x32_f16(ah[2], wa[gt], acc[gt], 0, 0, 0);
#pragma unroll
        for (int gt = 0; gt < 4; ++gt)
          acc[gt] = __builtin_amdgcn_mfma_f32_16x16x32_f16(ah[3], wb[gt], acc[gt], 0, 0, 0);
#pragma unroll
        for (int kc = 0; kc < 4; ++kc)
#pragma unroll
          for (int gt = 0; gt < 4; ++gt)
            acc[gt] = __builtin_amdgcn_mfma_f32_16x16x32_f16(a1h[kc], bwhh1[grp][gt][kc], acc[gt], 0, 0, 0);
        GATES(acc, cI[grp], cF[grp], cG[grp], cO[grp], c1a[grp], c1b[grp],
              h1wr, grp ? hc1 : hc0);
      }
      asm volatile("s_waitcnt lgkmcnt(0)" ::: "memory");
    }
  }

  __syncthreads();   // converged join: h1(T_-1) visible to all waves

  // ---- FC head: out[row] = sum_c h1_last[row][c]*Wfc[c] + bfc ----
  // role-agnostic: wave w covers cols w*16+n (0..127); rows q and q+4.
  const int colg = w * 16 + n;
  const float wfcv = Wfc[colg];
  float p0 = (float)lds_h1[H0SZ + q * LSTR + colg] * wfcv;
  float p1 = (float)lds_h1[H0SZ + (q + 4) * LSTR + colg] * wfcv;
#pragma unroll
  for (int m = 1; m < 16; m <<= 1) {
    p0 += __shfl_xor(p0, m);
    p1 += __shfl_xor(p1, m);
  }
  if (n == 0) {
    lds_fc[w][q] = p0;
    lds_fc[w][q + 4] = p1;
  }
  __syncthreads();
  if (tid < 8) {
    float s = bfc[0];
#pragma unroll
    for (int wv = 0; wv < 8; ++wv) s += lds_fc[wv][tid];
    out[rbase + tid] = s;
  }
}

extern "C" void kernel_launch(void* const* d_in, const int* in_sizes, int n_in,
                              void* d_out, int out_size, void* d_ws, size_t ws_size,
                              hipStream_t stream) {
  const float* x    = (const float*)d_in[0];
  const float* Wih0 = (const float*)d_in[1];
  const float* Whh0 = (const float*)d_in[2];
  const float* b0   = (const float*)d_in[3];
  const float* Wih1 = (const float*)d_in[4];
  const float* Whh1 = (const float*)d_in[5];
  const float* b1   = (const float*)d_in[6];
  const float* Wfc  = (const float*)d_in[7];
  const float* bfc  = (const float*)d_in[8];
  float* outp = (float*)d_out;
  (void)d_ws; (void)ws_size;

  lstm_fused<<<B_ / 8, 512, 0, stream>>>(x, Wih0, Whh0, b0, Wih1, Whh1, b1,
                                         Wfc, bfc, outp);
}